// Round 5
// baseline (116.562 us; speedup 1.0000x reference)
//
#include <hip/hip_runtime.h>

// Problem constants (from reference): N=4096, D=512, C=100, P=64
#define D 512
#define D4 (D / 4)      // 128 float4 chunks per row
#define P 64
#define WPB 4           // waves per block
#define NB 2            // boxes per group (same class)
#define MAXC 256        // LDS histogram capacity (C=100)
#define EPS_COS 1e-8f
#define EPS_INV 1e-5f

__device__ __forceinline__ float wave_sum(float v) {
#pragma unroll
    for (int m = 32; m >= 1; m >>= 1) v += __shfl_xor(v, m, 64);
    return v;
}

// Fused prep:
//   blocks [0, trBlocks)            : LDS-tiled transpose protos -> protosT
//                                     (coalesced global read AND write; the
//                                     round-4 scatter-write was ~50 us)
//   blocks [trBlocks, +normBlocks)  : pp[r] = ||protos[r]||^2 (coalesced)
//   block  trBlocks+normBlocks     : counting-sort boxes into NB-groups
__global__ __launch_bounds__(256) void prep_kernel(
    const float* __restrict__ protos, float* __restrict__ pp,
    float* __restrict__ protosT, int rows,
    const int* __restrict__ cls_ids, int* __restrict__ slots,
    int* __restrict__ gcount, int N, int C, int trBlocks, int normBlocks)
{
    const int bid = blockIdx.x;

    if (bid < trBlocks) {
        // block = (c, g): d4 range [8g, 8g+8), all 64 protos of class c.
        __shared__ float4 tile[8][64];          // 8 KB; [chunk][proto]
        const int c = bid >> 4;                 // trBlocks = C*16
        const int g = bid & 15;
        const int tid = threadIdx.x;
        const int j  = tid & 7;                 // chunk within group
        const int p0 = tid >> 3;                // proto rows [0,32), [32,64)
#pragma unroll
        for (int h = 0; h < 2; ++h) {
            const int p = p0 + 32 * h;
            // per-inst: 8 consecutive threads read 128B contiguous of row p
            tile[j][p] = *(const float4*)(protos
                + (size_t)(c * P + p) * D + g * 32 + j * 4);
        }
        __syncthreads();
        const int lane = tid & 63, w = tid >> 6;
        float4* outp = (float4*)protosT + ((size_t)c * D4 + g * 8) * P;
#pragma unroll
        for (int k = 0; k < 2; ++k) {
            const int jl = 2 * w + k;
            // 1KB contiguous store per (wave, jl)
            outp[(size_t)jl * P + lane] = tile[jl][lane];
        }
        return;
    }

    if (bid < trBlocks + normBlocks) {
        const int lane = threadIdx.x & 63;
        const int wave = threadIdx.x >> 6;
        const int r = (bid - trBlocks) * WPB + wave;
        if (r >= rows) return;
        const float* row = protos + (size_t)r * D;
        const float4 a = *(const float4*)(row + lane * 4);
        const float4 b = *(const float4*)(row + 256 + lane * 4);
        float s = a.x*a.x + a.y*a.y + a.z*a.z + a.w*a.w
                + b.x*b.x + b.y*b.y + b.z*b.z + b.w*b.w;
        s = wave_sum(s);
        if (lane == 0) pp[r] = s;
        return;
    }

    // ---- build path: single block, 256 threads ----
    __shared__ int cnt[MAXC], bas[MAXC], fil[MAXC];
    __shared__ int sv[256];
    const int tid = threadIdx.x;
    for (int c = tid; c < MAXC; c += 256) { cnt[c] = 0; fil[c] = 0; }
    __syncthreads();
    for (int n = tid; n < N; n += 256) atomicAdd(&cnt[cls_ids[n]], 1);
    __syncthreads();
    int v = 0;
    if (tid < C) v = (cnt[tid] + NB - 1) / NB;
    sv[tid] = v;
    __syncthreads();
#pragma unroll
    for (int off = 1; off < 256; off <<= 1) {
        const int t = (tid >= off) ? sv[tid - off] : 0;
        __syncthreads();
        sv[tid] += t;
        __syncthreads();
    }
    const int G = sv[255];                 // total groups
    if (tid < C) bas[tid] = sv[tid] - v;   // exclusive scan
    if (tid == 0) gcount[0] = G;
    __syncthreads();
    for (int i = tid; i < G * NB; i += 256) slots[i] = -1;
    __syncthreads();
    for (int n = tid; n < N; n += 256) {
        const int c = cls_ids[n];
        const int p = atomicAdd(&fil[c], 1);
        slots[bas[c] * NB + p] = n;
    }
}

__device__ __forceinline__ void box_epilogue(
    float r_dot, float r_l1, float ff, float s_pp, int myp,
    float& prob_o, int& bidx_o)
{
    const float fnorm = fmaxf(sqrtf(ff),   EPS_COS);
    const float pnorm = fmaxf(sqrtf(s_pp), EPS_COS);
    const float d_cos = 1.0f - r_dot / (fnorm * pnorm);
    const float d_l1  = r_l1 * (1.0f / (float)D);
    const float d_l2  = (ff - 2.0f * r_dot + s_pp) * (1.0f / (float)D);

    float s[3];
    s[0] = 1.0f / (d_cos + EPS_INV);
    s[1] = 1.0f / (d_l1  + EPS_INV);
    s[2] = 1.0f / (d_l2  + EPS_INV);

    float prob = 0.f;
#pragma unroll
    for (int i = 0; i < 3; ++i) {
        float m = s[i];
#pragma unroll
        for (int w = 32; w >= 1; w >>= 1) m = fmaxf(m, __shfl_xor(m, w, 64));
        const float e = expf(s[i] - m);
        const float denom = wave_sum(e);
        prob += e / denom;
    }
    prob *= (1.0f / 3.0f);

    // argmax over protos, first-index tie-break
    float best = prob;
    int   bidx = myp;
#pragma unroll
    for (int w = 32; w >= 1; w >>= 1) {
        const float ov = __shfl_xor(best, w, 64);
        const int   oi = __shfl_xor(bidx, w, 64);
        if (ov > best || (ov == best && oi < bidx)) { best = ov; bidx = oi; }
    }
    prob_o = prob;
    bidx_o = bidx;
}

// Main kernel: one wave per NB=2 same-class boxes; LANE p OWNS PROTO p.
// D processed in 16 chunks of 8 float4s with explicit double-buffering:
// next chunk's loads issue BEFORE current chunk's ~192 VALU ops -> MLP ~24.
__global__ __launch_bounds__(WPB * 64) void proto_probs_kernel(
    const float* __restrict__ feats,        // [N, D]
    const float* __restrict__ protosT,      // [C][D4][P][4]
    const int*   __restrict__ cls_ids,      // [N]
    const int*   __restrict__ proto_labels, // [C, P]
    const float* __restrict__ ppbuf,        // [C*P] ||p||^2
    const int*   __restrict__ slots,        // [G*NB] box ids (-1 pad)
    const int*   __restrict__ gcount,       // [1] G
    float* __restrict__ out,                // [N] labels ++ [N, P] probs
    int N)
{
    const int lane = threadIdx.x & 63;
    const int wave = threadIdx.x >> 6;

    // Bijective chunked XCD swizzle (m204): class runs stay on one XCD's L2.
    const int nbk = gridDim.x;
    const int q   = nbk >> 3, r = nbk & 7;
    const int xcd = blockIdx.x & 7, bix = blockIdx.x >> 3;
    const int swz = (xcd < r ? xcd * (q + 1) : r * (q + 1) + (xcd - r) * q) + bix;

    const int g = swz * WPB + wave;
    if (g >= gcount[0]) return;

    const int b0 = __builtin_amdgcn_readfirstlane(slots[NB * g]);
    const int b1 = __builtin_amdgcn_readfirstlane(slots[NB * g + 1]);
    const bool v1 = (b1 >= 0);
    const int n0 = b0;
    const int n1 = v1 ? b1 : b0;
    const int cls = __builtin_amdgcn_readfirstlane(cls_ids[n0]);

    const float*  fA  = feats + (size_t)n0 * D;
    const float*  fB  = feats + (size_t)n1 * D;
    const float4* fA4 = (const float4*)fA;
    const float4* fB4 = (const float4*)fB;
    const float4* pT4 = (const float4*)protosT + (size_t)cls * (D4 * P);

    // feat self-norms (distributed coalesced read + one wave reduction each)
    float ffA, ffB;
    {
        const float4 a0 = *(const float4*)(fA + lane * 4);
        const float4 a1 = *(const float4*)(fA + 256 + lane * 4);
        ffA = wave_sum(a0.x*a0.x + a0.y*a0.y + a0.z*a0.z + a0.w*a0.w
                     + a1.x*a1.x + a1.y*a1.y + a1.z*a1.z + a1.w*a1.w);
        const float4 c0 = *(const float4*)(fB + lane * 4);
        const float4 c1 = *(const float4*)(fB + 256 + lane * 4);
        ffB = wave_sum(c0.x*c0.x + c0.y*c0.y + c0.z*c0.z + c0.w*c0.w
                     + c1.x*c1.x + c1.y*c1.y + c1.z*c1.z + c1.w*c1.w);
    }

    float dotA = 0.f, l1A = 0.f, dotB = 0.f, l1B = 0.f;

    float4 qc[8], ac[8], bc[8];
#pragma unroll
    for (int j = 0; j < 8; ++j) qc[j] = pT4[j * P + lane];
#pragma unroll
    for (int j = 0; j < 8; ++j) { ac[j] = fA4[j]; bc[j] = fB4[j]; }

#pragma unroll 1
    for (int c = 0; c < 16; ++c) {
        float4 qn[8], an[8], bn[8];
        const int nc = (c + 1) & 15;   // last iter reloads chunk 0 (in-bounds, unused)
#pragma unroll
        for (int j = 0; j < 8; ++j) qn[j] = pT4[(nc * 8 + j) * P + lane];
#pragma unroll
        for (int j = 0; j < 8; ++j) { an[j] = fA4[nc * 8 + j]; bn[j] = fB4[nc * 8 + j]; }
#pragma unroll
        for (int j = 0; j < 8; ++j) {
            float t;
            dotA += ac[j].x*qc[j].x; t = ac[j].x - qc[j].x; l1A += fabsf(t);
            dotA += ac[j].y*qc[j].y; t = ac[j].y - qc[j].y; l1A += fabsf(t);
            dotA += ac[j].z*qc[j].z; t = ac[j].z - qc[j].z; l1A += fabsf(t);
            dotA += ac[j].w*qc[j].w; t = ac[j].w - qc[j].w; l1A += fabsf(t);
            dotB += bc[j].x*qc[j].x; t = bc[j].x - qc[j].x; l1B += fabsf(t);
            dotB += bc[j].y*qc[j].y; t = bc[j].y - qc[j].y; l1B += fabsf(t);
            dotB += bc[j].z*qc[j].z; t = bc[j].z - qc[j].z; l1B += fabsf(t);
            dotB += bc[j].w*qc[j].w; t = bc[j].w - qc[j].w; l1B += fabsf(t);
        }
#pragma unroll
        for (int j = 0; j < 8; ++j) { qc[j] = qn[j]; ac[j] = an[j]; bc[j] = bn[j]; }
    }

    const float s_pp = ppbuf[cls * P + lane];   // lane p owns proto p

    float probA; int bidxA;
    box_epilogue(dotA, l1A, ffA, s_pp, lane, probA, bidxA);
    out[(size_t)N + (size_t)n0 * P + lane] = probA;
    if (lane == 0) out[n0] = (float)proto_labels[cls * P + bidxA];

    if (v1) {
        float probB; int bidxB;
        box_epilogue(dotB, l1B, ffB, s_pp, lane, probB, bidxB);
        out[(size_t)N + (size_t)n1 * P + lane] = probB;
        if (lane == 0) out[n1] = (float)proto_labels[cls * P + bidxB];
    }
}

extern "C" void kernel_launch(void* const* d_in, const int* in_sizes, int n_in,
                              void* d_out, int out_size, void* d_ws, size_t ws_size,
                              hipStream_t stream) {
    const float* feats        = (const float*)d_in[0];
    const float* protos       = (const float*)d_in[1];
    const int*   cls_ids      = (const int*)d_in[2];
    const int*   proto_labels = (const int*)d_in[3];
    float* out = (float*)d_out;

    const int N    = in_sizes[2];           // 4096
    const int rows = in_sizes[1] / D;       // C*P = 6400
    const int C    = rows / P;              // 100
    const int Gmax = (N + C * (NB - 1)) / NB;

    // Workspace: pp[rows] f32 | gcount[1] | slots[Gmax*NB] | pad | protosT[C*D*P]
    float* pp     = (float*)d_ws;
    int*   gcount = (int*)(pp + rows);
    int*   slots  = gcount + 1;
    size_t off = (size_t)rows * 4 + 4 + (size_t)Gmax * NB * 4;
    off = (off + 255) & ~(size_t)255;
    float* protosT = (float*)((char*)d_ws + off);

    const int trBlocks   = C * (D4 / 8);                  // 1600
    const int normBlocks = (rows + WPB - 1) / WPB;        // 1600
    const int mainBlocks = (Gmax + WPB - 1) / WPB;        // ~537

    prep_kernel<<<trBlocks + normBlocks + 1, 256, 0, stream>>>(
        protos, pp, protosT, rows, cls_ids, slots, gcount, N, C,
        trBlocks, normBlocks);
    proto_probs_kernel<<<mainBlocks, WPB * 64, 0, stream>>>(
        feats, protosT, cls_ids, proto_labels, pp, slots, gcount, out, N);
}

// Round 6
// 112.420 us; speedup vs baseline: 1.0368x; 1.0368x over previous
//
#include <hip/hip_runtime.h>

// Problem constants (from reference): N=4096, D=512, C=100, P=64
#define D 512
#define D4 (D / 4)      // 128 float4 chunks per feature row
#define P 64
#define WPB 4           // waves per block (norm path + main)
#define BPB 8           // boxes per main block (4 waves x 2 boxes)
#define MAXC 256        // LDS histogram capacity (C=100)
#define EPS_COS 1e-8f
#define EPS_INV 1e-5f

__device__ __forceinline__ float wave_sum(float v) {
#pragma unroll
    for (int m = 32; m >= 1; m >>= 1) v += __shfl_xor(v, m, 64);
    return v;
}

// Fused prep:
//   blocks [0, normBlocks) : pp[r] = ||protos[r]||^2
//   block  normBlocks      : counting-sort boxes into same-class BLOCKS of 8
//                            (blockClass[b], slots[b*8+k], bcount[0]=B)
__global__ __launch_bounds__(256) void prep_kernel(
    const float* __restrict__ protos, float* __restrict__ pp, int rows,
    const int* __restrict__ cls_ids, int* __restrict__ bcount,
    int* __restrict__ blockClass, int* __restrict__ slots,
    int N, int C, int normBlocks)
{
    const int bid = blockIdx.x;

    if (bid < normBlocks) {
        const int lane = threadIdx.x & 63;
        const int wave = threadIdx.x >> 6;
        const int r = bid * WPB + wave;
        if (r >= rows) return;
        const float* row = protos + (size_t)r * D;
        const float4 a = *(const float4*)(row + lane * 4);
        const float4 b = *(const float4*)(row + 256 + lane * 4);
        float s = a.x*a.x + a.y*a.y + a.z*a.z + a.w*a.w
                + b.x*b.x + b.y*b.y + b.z*b.z + b.w*b.w;
        s = wave_sum(s);
        if (lane == 0) pp[r] = s;
        return;
    }

    // ---- build path: single block, 256 threads ----
    __shared__ int cnt[MAXC], blkb[MAXC], fil[MAXC];
    __shared__ int sv[256];
    const int tid = threadIdx.x;
    for (int c = tid; c < MAXC; c += 256) { cnt[c] = 0; fil[c] = 0; }
    __syncthreads();
    for (int n = tid; n < N; n += 256) atomicAdd(&cnt[cls_ids[n]], 1);
    __syncthreads();
    int v = 0;
    if (tid < C) v = (cnt[tid] + BPB - 1) / BPB;   // blocks for this class
    sv[tid] = v;
    __syncthreads();
#pragma unroll
    for (int off = 1; off < 256; off <<= 1) {
        const int t = (tid >= off) ? sv[tid - off] : 0;
        __syncthreads();
        sv[tid] += t;
        __syncthreads();
    }
    const int B = sv[255];                  // total main blocks
    if (tid < C) blkb[tid] = sv[tid] - v;   // exclusive scan
    if (tid == 0) bcount[0] = B;
    __syncthreads();
    if (tid < C) {
        const int nb = (cnt[tid] + BPB - 1) / BPB;
        const int b0 = blkb[tid];
        for (int k = 0; k < nb; ++k) blockClass[b0 + k] = tid;
    }
    for (int i = tid; i < B * BPB; i += 256) slots[i] = -1;
    __syncthreads();
    for (int n = tid; n < N; n += 256) {
        const int c = cls_ids[n];
        const int r = atomicAdd(&fil[c], 1);
        slots[(blkb[c] + (r >> 3)) * BPB + (r & 7)] = n;
    }
}

__device__ __forceinline__ void box_epilogue(
    float r_dot, float r_l1, float ff, float s_pp, int myp,
    float& prob_o, int& bidx_o)
{
    const float fnorm = fmaxf(sqrtf(ff),   EPS_COS);
    const float pnorm = fmaxf(sqrtf(s_pp), EPS_COS);
    const float d_cos = 1.0f - r_dot / (fnorm * pnorm);
    const float d_l1  = r_l1 * (1.0f / (float)D);
    const float d_l2  = (ff - 2.0f * r_dot + s_pp) * (1.0f / (float)D);

    float s[3];
    s[0] = 1.0f / (d_cos + EPS_INV);
    s[1] = 1.0f / (d_l1  + EPS_INV);
    s[2] = 1.0f / (d_l2  + EPS_INV);

    float prob = 0.f;
#pragma unroll
    for (int i = 0; i < 3; ++i) {
        float m = s[i];
#pragma unroll
        for (int w = 32; w >= 1; w >>= 1) m = fmaxf(m, __shfl_xor(m, w, 64));
        const float e = expf(s[i] - m);
        const float denom = wave_sum(e);
        prob += e / denom;
    }
    prob *= (1.0f / 3.0f);

    // argmax over protos, first-index tie-break
    float best = prob;
    int   bidx = myp;
#pragma unroll
    for (int w = 32; w >= 1; w >>= 1) {
        const float ov = __shfl_xor(best, w, 64);
        const int   oi = __shfl_xor(bidx, w, 64);
        if (ov > best || (ov == best && oi < bidx)) { best = ov; bidx = oi; }
    }
    prob_o = prob;
    bidx_o = bidx;
}

// Main kernel: one block per 8 SAME-CLASS boxes (4 waves x 2). Protos stream
// from the pristine row-major tensor through a double-buffered LDS chunk
// (8 d4 x 64 protos = 8KB); all 4 waves consume each chunk -> 4x less L2
// traffic, no transpose prep, no dirty cross-XCD lines. Lane p owns proto p.
__global__ __launch_bounds__(WPB * 64) void proto_probs_kernel(
    const float* __restrict__ feats,        // [N, D]
    const float* __restrict__ protos,       // [C, P, D]
    const int*   __restrict__ proto_labels, // [C, P]
    const float* __restrict__ ppbuf,        // [C*P] ||p||^2
    const int*   __restrict__ bcount,       // [1] B
    const int*   __restrict__ blockClass,   // [B]
    const int*   __restrict__ slots,        // [B*8] box ids (-1 pad)
    float* __restrict__ out,                // [N] labels ++ [N, P] probs
    int N)
{
    const int tid  = threadIdx.x;
    const int lane = tid & 63;
    const int w    = tid >> 6;

    // Bijective chunked XCD swizzle (m204): each XCD gets a contiguous run of
    // blocks -> a class's ~6 blocks share one XCD's L2.
    const int nbk = gridDim.x;
    const int q   = nbk >> 3, r = nbk & 7;
    const int xcd = blockIdx.x & 7, bix = blockIdx.x >> 3;
    const int b   = (xcd < r ? xcd * (q + 1) : r * (q + 1) + (xcd - r) * q) + bix;

    if (b >= bcount[0]) return;   // uniform per block

    const int cls = __builtin_amdgcn_readfirstlane(blockClass[b]);
    const int s0  = __builtin_amdgcn_readfirstlane(slots[b * BPB]);
    const int k0  = __builtin_amdgcn_readfirstlane(slots[b * BPB + 2 * w]);
    const int k1  = __builtin_amdgcn_readfirstlane(slots[b * BPB + 2 * w + 1]);
    const int n0  = (k0 >= 0) ? k0 : s0;    // dup slot0 for pad waves (no write)
    const int n1  = (k1 >= 0) ? k1 : s0;

    __shared__ float4 fLds[BPB * D4];       // 16 KB: 8 boxes' feats
    __shared__ float4 pbuf[2 * 8 * P];      // 16 KB: 2 x (8 f4-chunks x 64 protos)

    const float4* feats4 = (const float4*)feats;
    const float*  prC    = protos + (size_t)cls * (P * D);

    // stage 8 boxes' feats -> LDS (linear, conflict-free)
#pragma unroll
    for (int u = 0; u < 4; ++u) {
        const int i  = tid + 256 * u;       // [0, 1024)
        const int bx = i >> 7;
        int nb = slots[b * BPB + bx];
        if (nb < 0) nb = s0;
        fLds[i] = feats4[(size_t)nb * D4 + (i & 127)];
    }

    // stage proto chunk 0 -> pbuf[0]; layout pbuf[buf*512 + j*64 + p]
    const int jj  = tid & 7;                // f4 within chunk
    const int pp0 = tid >> 3;               // proto row base [0,32)
    {
        const float4 r0 = *(const float4*)(prC + (size_t)pp0 * D + jj * 4);
        const float4 r1 = *(const float4*)(prC + (size_t)(pp0 + 32) * D + jj * 4);
        pbuf[jj * 64 + pp0]      = r0;
        pbuf[jj * 64 + pp0 + 32] = r1;
    }
    __syncthreads();

    // feat self-norms from LDS (same values/order as global read)
    float ffA, ffB;
    {
        const float4 a0 = fLds[(2 * w) * D4 + lane];
        const float4 a1 = fLds[(2 * w) * D4 + 64 + lane];
        ffA = wave_sum(a0.x*a0.x + a0.y*a0.y + a0.z*a0.z + a0.w*a0.w
                     + a1.x*a1.x + a1.y*a1.y + a1.z*a1.z + a1.w*a1.w);
        const float4 c0 = fLds[(2 * w + 1) * D4 + lane];
        const float4 c1 = fLds[(2 * w + 1) * D4 + 64 + lane];
        ffB = wave_sum(c0.x*c0.x + c0.y*c0.y + c0.z*c0.z + c0.w*c0.w
                     + c1.x*c1.x + c1.y*c1.y + c1.z*c1.z + c1.w*c1.w);
    }

    float dotA = 0.f, l1A = 0.f, dotB = 0.f, l1B = 0.f;

#pragma unroll 1
    for (int c = 0; c < 16; ++c) {
        const int cur = c & 1;
        float4 s0r, s1r;
        if (c < 15) {   // issue next chunk's global loads early (T14)
            s0r = *(const float4*)(prC + (size_t)pp0 * D + (c + 1) * 32 + jj * 4);
            s1r = *(const float4*)(prC + (size_t)(pp0 + 32) * D + (c + 1) * 32 + jj * 4);
        }
#pragma unroll
        for (int j = 0; j < 8; ++j) {
            const float4 qv = pbuf[cur * 512 + j * 64 + lane];       // consecutive
            const float4 av = fLds[(2 * w) * D4 + c * 8 + j];        // broadcast
            const float4 bv = fLds[(2 * w + 1) * D4 + c * 8 + j];    // broadcast
            float t;
            dotA += av.x*qv.x; t = av.x - qv.x; l1A += fabsf(t);
            dotA += av.y*qv.y; t = av.y - qv.y; l1A += fabsf(t);
            dotA += av.z*qv.z; t = av.z - qv.z; l1A += fabsf(t);
            dotA += av.w*qv.w; t = av.w - qv.w; l1A += fabsf(t);
            dotB += bv.x*qv.x; t = bv.x - qv.x; l1B += fabsf(t);
            dotB += bv.y*qv.y; t = bv.y - qv.y; l1B += fabsf(t);
            dotB += bv.z*qv.z; t = bv.z - qv.z; l1B += fabsf(t);
            dotB += bv.w*qv.w; t = bv.w - qv.w; l1B += fabsf(t);
        }
        if (c < 15) {   // write next chunk to the other buffer (no clobber)
            pbuf[(cur ^ 1) * 512 + jj * 64 + pp0]      = s0r;
            pbuf[(cur ^ 1) * 512 + jj * 64 + pp0 + 32] = s1r;
        }
        __syncthreads();
    }

    const float s_pp = ppbuf[cls * P + lane];   // lane p owns proto p

    float probA; int bidxA;
    box_epilogue(dotA, l1A, ffA, s_pp, lane, probA, bidxA);
    if (k0 >= 0) {
        out[(size_t)N + (size_t)n0 * P + lane] = probA;
        if (lane == 0) out[n0] = (float)proto_labels[cls * P + bidxA];
    }
    if (k1 >= 0) {
        float probB; int bidxB;
        box_epilogue(dotB, l1B, ffB, s_pp, lane, probB, bidxB);
        out[(size_t)N + (size_t)n1 * P + lane] = probB;
        if (lane == 0) out[n1] = (float)proto_labels[cls * P + bidxB];
    }
}

extern "C" void kernel_launch(void* const* d_in, const int* in_sizes, int n_in,
                              void* d_out, int out_size, void* d_ws, size_t ws_size,
                              hipStream_t stream) {
    const float* feats        = (const float*)d_in[0];
    const float* protos       = (const float*)d_in[1];
    const int*   cls_ids      = (const int*)d_in[2];
    const int*   proto_labels = (const int*)d_in[3];
    float* out = (float*)d_out;

    const int N    = in_sizes[2];           // 4096
    const int rows = in_sizes[1] / D;       // C*P = 6400
    const int C    = rows / P;              // 100
    const int Bmax = (N + BPB - 1) / BPB + C;   // upper bound on main blocks

    // Workspace: pp[rows] f32 | bcount[1] | blockClass[Bmax] | slots[Bmax*8]
    float* pp         = (float*)d_ws;
    int*   bcount     = (int*)(pp + rows);
    int*   blockClass = bcount + 1;
    int*   slots      = blockClass + Bmax;

    const int normBlocks = (rows + WPB - 1) / WPB;        // 1600

    prep_kernel<<<normBlocks + 1, 256, 0, stream>>>(
        protos, pp, rows, cls_ids, bcount, blockClass, slots, N, C, normBlocks);
    proto_probs_kernel<<<Bmax, WPB * 64, 0, stream>>>(
        feats, protos, proto_labels, pp, bcount, blockClass, slots, out, N);
}

// Round 7
// 111.132 us; speedup vs baseline: 1.0489x; 1.0116x over previous
//
#include <hip/hip_runtime.h>

// Problem constants (from reference): N=4096, D=512, C=100, P=64
#define D 512
#define D4 128          // float4 chunks per row
#define P 64
#define NCHUNK 16       // 16 chunks x 8 float4 (32 floats) = D
#define SPB 8           // batch-stripes per class -> grid = C * SPB
#define EPS_COS 1e-8f
#define EPS_INV 1e-5f

__device__ __forceinline__ float wave_sum(float v) {
#pragma unroll
    for (int m = 32; m >= 1; m >>= 1) v += __shfl_xor(v, m, 64);
    return v;
}

__device__ __forceinline__ float dot4(const float4 a, const float4 b) {
    return a.x*b.x + a.y*b.y + a.z*b.z + a.w*b.w;
}

__device__ __forceinline__ void box_epilogue(
    float r_dot, float r_l1, float ff, float s_pp, int myp,
    float& prob_o, int& bidx_o)
{
    const float fnorm = fmaxf(sqrtf(ff),   EPS_COS);
    const float pnorm = fmaxf(sqrtf(s_pp), EPS_COS);
    const float d_cos = 1.0f - r_dot / (fnorm * pnorm);
    const float d_l1  = r_l1 * (1.0f / (float)D);
    const float d_l2  = (ff - 2.0f * r_dot + s_pp) * (1.0f / (float)D);

    float s[3];
    s[0] = 1.0f / (d_cos + EPS_INV);
    s[1] = 1.0f / (d_l1  + EPS_INV);
    s[2] = 1.0f / (d_l2  + EPS_INV);

    float prob = 0.f;
#pragma unroll
    for (int i = 0; i < 3; ++i) {
        float m = s[i];
#pragma unroll
        for (int w = 32; w >= 1; w >>= 1) m = fmaxf(m, __shfl_xor(m, w, 64));
        const float e = expf(s[i] - m);
        const float denom = wave_sum(e);
        prob += e / denom;
    }
    prob *= (1.0f / 3.0f);

    // argmax over protos, first-index tie-break
    float best = prob;
    int   bidx = myp;
#pragma unroll
    for (int w = 32; w >= 1; w >>= 1) {
        const float ov = __shfl_xor(best, w, 64);
        const int   oi = __shfl_xor(bidx, w, 64);
        if (ov > best || (ov == best && oi < bidx)) { best = ov; bidx = oi; }
    }
    prob_o = prob;
    bidx_o = bidx;
}

// ONE kernel, ONE dispatch. Block (c, s): finds boxes of class c with batch
// index % SPB == s by scanning cls_ids (16 KB, L2-broadcast), then runs the
// round-6 LDS proto-stream pipeline on batches of 8 same-class boxes.
// Proto self-norms computed for free during staging (qq += r.r).
// No sort kernel, no norm kernel, no workspace, no inter-kernel drains.
__global__ __launch_bounds__(256) void fused_kernel(
    const float* __restrict__ feats,        // [N, D]
    const float* __restrict__ protos,       // [C, P, D]
    const int*   __restrict__ cls_ids,      // [N]
    const int*   __restrict__ proto_labels, // [C, P]
    float* __restrict__ out,                // [N] labels ++ [N, P] probs
    int N, int C)
{
    const int tid  = threadIdx.x;
    const int lane = tid & 63;
    const int w    = tid >> 6;

    // Bijective chunked XCD swizzle (m204): a class's 8 stripe-blocks land on
    // (mostly) one XCD -> its 128 KB proto set stays in that XCD's L2.
    const int nbk = gridDim.x;
    const int q   = nbk >> 3, r = nbk & 7;
    const int xcd = blockIdx.x & 7, bix = blockIdx.x >> 3;
    const int id  = (xcd < r ? xcd * (q + 1) : r * (q + 1) + (xcd - r) * q) + bix;
    const int cls = id >> 3;                // SPB = 8
    const int s   = id & 7;
    if (cls >= C) return;

    __shared__ float4 pbuf[2 * 8 * P];      // 16 KB proto double-buffer
    __shared__ int    sc[256];              // scan scratch
    __shared__ int    boxIds[512];          // rank -> box id (local batches)
    __shared__ float  ppLds[P];             // ||proto||^2

    // ---- setup: find this block's boxes (no global sort) ----
    // thread t owns cls_ids[16t .. 16t+16)
    unsigned mask = 0;
    const int base = tid * 16;
    {
#pragma unroll
        for (int k = 0; k < 16; k += 4) {
            if (base + k + 3 < N) {
                const int4 v = *(const int4*)(cls_ids + base + k);
                if (v.x == cls) mask |= 1u << (k + 0);
                if (v.y == cls) mask |= 1u << (k + 1);
                if (v.z == cls) mask |= 1u << (k + 2);
                if (v.w == cls) mask |= 1u << (k + 3);
            } else {
                for (int kk = k; kk < k + 4; ++kk)
                    if (base + kk < N && cls_ids[base + kk] == cls)
                        mask |= 1u << kk;
            }
        }
    }
    const int cnt = __popc(mask);
    sc[tid] = cnt;
    boxIds[tid] = -1;
    boxIds[tid + 256] = -1;
    __syncthreads();
#pragma unroll
    for (int off = 1; off < 256; off <<= 1) {
        const int t = (tid >= off) ? sc[tid - off] : 0;
        __syncthreads();
        sc[tid] += t;
        __syncthreads();
    }
    const int myBase = sc[tid] - cnt;
    const int total  = sc[255];
    // push: rank rk -> batch b = rk>>3; block s owns b%8==s; local L = b>>3
    {
        int rk = myBase;
        unsigned m2 = mask;
        while (m2) {
            const int k = __ffs(m2) - 1; m2 &= m2 - 1;
            if (((rk >> 3) & 7) == s)
                boxIds[((rk >> 6) << 3) | (rk & 7)] = base + k;
            ++rk;
        }
    }
    __syncthreads();

    const int nb_total = (total + 7) >> 3;
    const int nLoc = (nb_total > s) ? (((nb_total - 1 - s) >> 3) + 1) : 0;
    if (nLoc == 0) return;                  // uniform exit

    const float*  prC    = protos + (size_t)cls * (P * D);
    const float4* feats4 = (const float4*)feats;
    const int jj  = tid & 7;                // f4-slot within chunk
    const int pp0 = tid >> 3;               // proto rows pp0, pp0+32

    float qq0 = 0.f, qq1 = 0.f;             // ||proto||^2 partials (L==0)

    for (int L = 0; L < nLoc; ++L) {
        const int sb    = L * 8;
        const int first = __builtin_amdgcn_readfirstlane(boxIds[sb]);
        const int k0    = __builtin_amdgcn_readfirstlane(boxIds[sb + 2 * w]);
        const int k1    = __builtin_amdgcn_readfirstlane(boxIds[sb + 2 * w + 1]);
        const int n0 = (k0 >= 0) ? k0 : first;
        const int n1 = (k1 >= 0) ? k1 : first;

        const float4* f0 = feats4 + (size_t)n0 * D4;
        const float4* f1 = feats4 + (size_t)n1 * D4;

        // stage chunk 0
        {
            const float4 r0 = *(const float4*)(prC + (size_t)pp0 * D + jj * 4);
            const float4 r1 = *(const float4*)(prC + (size_t)(pp0 + 32) * D + jj * 4);
            if (L == 0) { qq0 += dot4(r0, r0); qq1 += dot4(r1, r1); }
            pbuf[jj * 64 + pp0]      = r0;
            pbuf[jj * 64 + pp0 + 32] = r1;
        }

        // feat self-norms (lane-strided coalesced + butterfly, as before)
        float ffA, ffB;
        {
            const float4 a0 = f0[lane], a1 = f0[64 + lane];
            ffA = wave_sum(dot4(a0, a0) + dot4(a1, a1));
            const float4 c0 = f1[lane], c1 = f1[64 + lane];
            ffB = wave_sum(dot4(c0, c0) + dot4(c1, c1));
        }
        __syncthreads();

        float dotA = 0.f, l1A = 0.f, dotB = 0.f, l1B = 0.f;

#pragma unroll 1
        for (int c = 0; c < NCHUNK; ++c) {
            const int cur = c & 1;
            float4 s0r, s1r;
            if (c < NCHUNK - 1) {           // prefetch next chunk (issue early)
                s0r = *(const float4*)(prC + (size_t)pp0 * D + (c + 1) * 32 + jj * 4);
                s1r = *(const float4*)(prC + (size_t)(pp0 + 32) * D + (c + 1) * 32 + jj * 4);
            }
#pragma unroll
            for (int j = 0; j < 8; ++j) {
                const float4 qv = pbuf[cur * 512 + j * 64 + lane];
                const float4 av = f0[c * 8 + j];    // wave-uniform
                const float4 bv = f1[c * 8 + j];    // wave-uniform
                float t;
                dotA += av.x*qv.x; t = av.x - qv.x; l1A += fabsf(t);
                dotA += av.y*qv.y; t = av.y - qv.y; l1A += fabsf(t);
                dotA += av.z*qv.z; t = av.z - qv.z; l1A += fabsf(t);
                dotA += av.w*qv.w; t = av.w - qv.w; l1A += fabsf(t);
                dotB += bv.x*qv.x; t = bv.x - qv.x; l1B += fabsf(t);
                dotB += bv.y*qv.y; t = bv.y - qv.y; l1B += fabsf(t);
                dotB += bv.z*qv.z; t = bv.z - qv.z; l1B += fabsf(t);
                dotB += bv.w*qv.w; t = bv.w - qv.w; l1B += fabsf(t);
            }
            if (c < NCHUNK - 1) {
                if (L == 0) { qq0 += dot4(s0r, s0r); qq1 += dot4(s1r, s1r); }
                pbuf[(cur ^ 1) * 512 + jj * 64 + pp0]      = s0r;
                pbuf[(cur ^ 1) * 512 + jj * 64 + pp0 + 32] = s1r;
            }
            __syncthreads();
        }

        if (L == 0) {
            // reduce qq over the 8 jj-threads sharing each proto row
#pragma unroll
            for (int m = 1; m <= 4; m <<= 1) {
                qq0 += __shfl_xor(qq0, m, 64);
                qq1 += __shfl_xor(qq1, m, 64);
            }
            if ((lane & 7) == 0) { ppLds[pp0] = qq0; ppLds[pp0 + 32] = qq1; }
            __syncthreads();
        }

        const float s_pp = ppLds[lane];     // lane p owns proto p

        float probA; int bidxA;
        box_epilogue(dotA, l1A, ffA, s_pp, lane, probA, bidxA);
        if (k0 >= 0) {
            out[(size_t)N + (size_t)n0 * P + lane] = probA;
            if (lane == 0) out[n0] = (float)proto_labels[cls * P + bidxA];
        }
        if (k1 >= 0) {
            float probB; int bidxB;
            box_epilogue(dotB, l1B, ffB, s_pp, lane, probB, bidxB);
            out[(size_t)N + (size_t)n1 * P + lane] = probB;
            if (lane == 0) out[n1] = (float)proto_labels[cls * P + bidxB];
        }
    }
}

extern "C" void kernel_launch(void* const* d_in, const int* in_sizes, int n_in,
                              void* d_out, int out_size, void* d_ws, size_t ws_size,
                              hipStream_t stream) {
    const float* feats        = (const float*)d_in[0];
    const float* protos       = (const float*)d_in[1];
    const int*   cls_ids      = (const int*)d_in[2];
    const int*   proto_labels = (const int*)d_in[3];
    float* out = (float*)d_out;

    const int N = in_sizes[2];                  // 4096
    const int C = in_sizes[1] / (D * P);        // 100

    fused_kernel<<<C * SPB, 256, 0, stream>>>(
        feats, protos, cls_ids, proto_labels, out, N, C);
}